// Round 4
// baseline (1184.772 us; speedup 1.0000x reference)
//
#include <hip/hip_runtime.h>
#include <math.h>

#define NS  1440000
#define LC  240         // chunk length
#define NCC 6000        // chunks per channel; LC*NCC == NS
#define CHB 94          // ceil(NCC/64) chunk-blocks per channel
#define CPW 51          // comp warm chunks = 12240 samples (proven ~12288 window)
#define EQW 9           // eq warm chunks = 2160 samples (worst pole^2160 ~ 5e-7)
#define CWIN (64 + CPW - 1 + 1)   // 115? -> warm-only window: 64+CPW-1 = 114
#define EWIN (64 + EQW - 1 + 1)   // warm-only window: 64+EQW-1 = 72
#define WPC 121         // padded LDS words per column (120 data words = 240 bf16)
#define U   24          // prefetch strip for output passes; 240 = 2*U*5

// ---- Reverb chain chunking ----
#define CB  128        // chain-steps per thread
#define RVW 40         // chain warm-up steps (0.6^40 ~ 1e-9)
#define FBC 0.6f       // feedback = 0.3 + 0.5*0.6

struct Coefs { float c[3][4][5]; };            // [stage][track][b0,b1,b2,a1,a2]
struct CompC { float atk, rel, oatk, orel, invt; };

// ===== Tiled transpose: x[ch][c*LC+s] -> XT[ch][s*NCC+c] =====
__global__ __launch_bounds__(256) void transpose_in(const float* __restrict__ x,
                                                    float* __restrict__ XT) {
  __shared__ float t[16][17];
  int b = blockIdx.x;
  int ch = b / (15 * 375);
  int r  = b % (15 * 375);
  int it = r / 375, jt = r % 375;      // s-tile, c-tile
  int tx = threadIdx.x & 15, ty = threadIdx.x >> 4;
  int s0 = it * 16, c0 = jt * 16;
  t[ty][tx] = x[(size_t)ch * NS + (size_t)(c0 + ty) * LC + (s0 + tx)];
  __syncthreads();
  XT[(size_t)ch * NS + (size_t)(s0 + ty) * NCC + (c0 + tx)] = t[tx][ty];
}

__device__ inline unsigned int f32_to_bf16_rtne(float v) {
  unsigned int b = __float_as_uint(v);
  return (b + 0x7fffu + ((b >> 16) & 1u)) >> 16;
}

// ===== EQ: lockstep-diagonal warm-up from bf16 LDS window, f32 output pass =====
#define EQ_STEP(VV)                                                        \
  {                                                                        \
    float v = (VV);                                                        \
    _Pragma("unroll")                                                      \
    for (int st = 0; st < 3; ++st) {                                       \
      float ya = fmaf(c[st][0], v, z[st][0]);                              \
      z[st][0] = fmaf(c[st][1], v, z[st][1]) - c[st][3] * ya;              \
      z[st][1] = fmaf(c[st][2], v, -(c[st][4] * ya));                      \
      v = ya;                                                              \
    }                                                                      \
    vout = v;                                                              \
  }

__global__ __launch_bounds__(64) void eq_kernel(const float* __restrict__ XT,
                                                float* __restrict__ ET, Coefs cf) {
  __shared__ unsigned int lds[EWIN * WPC];     // 72*121 words = 34.8 KB
  int blk = blockIdx.x;
  int ch = blk / CHB, cb = blk % CHB;
  int C0 = cb * 64;
  int lane = threadIdx.x;
  int tr = ch >> 1;
  float c[3][5];
  #pragma unroll
  for (int st = 0; st < 3; ++st)
    #pragma unroll
    for (int q = 0; q < 5; ++q) c[st][q] = cf.c[st][tr][q];
  const float* X = XT + (size_t)ch * NS;
  // ---- cooperative window fill (cols [C0-EQW, C0+63), signed bf16) ----
  for (int e = lane; e < EWIN * LC; e += 64) {
    int s = e / EWIN, cr = e - s * EWIN;
    int cg = C0 - EQW + cr;
    float v = (cg >= 0 && cg < NCC) ? X[(size_t)s * NCC + cg] : 0.f;
    ((unsigned short*)lds)[cr * (2 * WPC) + s] = (unsigned short)f32_to_bf16_rtne(v);
  }
  __syncthreads();
  float z[3][2] = {{0,0},{0,0},{0,0}};
  float vout;
  // ---- warm: step t processes column (lane + t) of the window ----
  for (int t = 0; t < EQW; ++t) {
    const unsigned int* p = lds + (lane + t) * WPC;
    #pragma unroll 4
    for (int sp = 0; sp < LC / 2; ++sp) {
      unsigned int wv = p[sp];
      float lo = __uint_as_float(wv << 16);
      float hi = __uint_as_float(wv & 0xffff0000u);
      EQ_STEP(lo);
      EQ_STEP(hi);
    }
  }
  (void)vout;
  // ---- output chunk: exact f32 reads (coalesced), coalesced stores ----
  int cg = C0 + lane;
  if (cg < NCC) {
    const float* p = X + cg;
    float* q = ET + (size_t)ch * NS + cg;
    float b0[U], b1[U];
    #pragma unroll
    for (int u = 0; u < U; ++u) b0[u] = p[(size_t)u * NCC];
    p += (size_t)U * NCC;
    for (int k = 0; k < 4; ++k) {
      #pragma unroll
      for (int u = 0; u < U; ++u) b1[u] = p[(size_t)u * NCC];
      p += (size_t)U * NCC;
      #pragma unroll
      for (int u = 0; u < U; ++u) { EQ_STEP(b0[u]); q[(size_t)u * NCC] = vout; }
      q += (size_t)U * NCC;
      #pragma unroll
      for (int u = 0; u < U; ++u) b0[u] = p[(size_t)u * NCC];
      p += (size_t)U * NCC;
      #pragma unroll
      for (int u = 0; u < U; ++u) { EQ_STEP(b1[u]); q[(size_t)u * NCC] = vout; }
      q += (size_t)U * NCC;
    }
    #pragma unroll
    for (int u = 0; u < U; ++u) b1[u] = p[(size_t)u * NCC];
    #pragma unroll
    for (int u = 0; u < U; ++u) { EQ_STEP(b0[u]); q[(size_t)u * NCC] = vout; }
    q += (size_t)U * NCC;
    #pragma unroll
    for (int u = 0; u < U; ++u) { EQ_STEP(b1[u]); q[(size_t)u * NCC] = vout; }
  }
}

// ===== Compressor: lockstep-diagonal warm-up (|x| bf16 in LDS), f32 output =====
__global__ __launch_bounds__(64) void comp_kernel(const float* __restrict__ ET,
                                                  float* __restrict__ Y, CompC cc) {
  __shared__ unsigned int lds[CWIN * WPC];     // 114*121 words = 55.2 KB
  int blk = blockIdx.x;
  int ch = blk / CHB, cb = blk % CHB;
  int C0 = cb * 64;
  int lane = threadIdx.x;
  const float* E = ET + (size_t)ch * NS;
  // ---- cooperative window fill (cols [C0-CPW, C0+63), |x| as bf16) ----
  for (int e = lane; e < CWIN * LC; e += 64) {
    int s = e / CWIN, cr = e - s * CWIN;
    int cg = C0 - CPW + cr;
    float v = (cg >= 0 && cg < NCC) ? E[(size_t)s * NCC + cg] : 0.f;
    unsigned int b = __float_as_uint(v) & 0x7fffffffu;   // abs
    b = (b + 0x7fffu + ((b >> 16) & 1u)) >> 16;
    ((unsigned short*)lds)[cr * (2 * WPC) + s] = (unsigned short)b;
  }
  __syncthreads();
  float env = 0.f;
  // ---- warm: step t processes column (lane + t); values already |x| ----
  for (int t = 0; t < CPW; ++t) {
    const unsigned int* p = lds + (lane + t) * WPC;
    #pragma unroll 4
    for (int sp = 0; sp < LC / 2; ++sp) {
      unsigned int wv = p[sp];
      float lo = __uint_as_float(wv << 16);
      float hi = __uint_as_float(wv & 0xffff0000u);
      float u1 = cc.oatk * lo, u2 = cc.orel * lo;
      env = fmaxf(fmaf(cc.atk, env, u1), fmaf(cc.rel, env, u2));
      u1 = cc.oatk * hi; u2 = cc.orel * hi;
      env = fmaxf(fmaf(cc.atk, env, u1), fmaf(cc.rel, env, u2));
    }
  }
  // ---- output chunk: exact f32 reads (coalesced), natural-layout writes ----
  int cg = C0 + lane;
  if (cg < NCC) {
    const float* p = E + cg;
    float* py = Y + (size_t)ch * NS + (size_t)cg * LC;
    float b0[U], b1[U];
    #pragma unroll
    for (int u = 0; u < U; ++u) b0[u] = p[(size_t)u * NCC];
    p += (size_t)U * NCC;
    #define CP_OUT(BUF)                                                       \
      _Pragma("unroll")                                                       \
      for (int u = 0; u < U; ++u) {                                           \
        float v = BUF[u];                                                     \
        float lvl = fabsf(v);                                                 \
        env = fmaxf(fmaf(cc.atk, env, cc.oatk * lvl),                         \
                    fmaf(cc.rel, env, cc.orel * lvl));                        \
        float m = fmaxf(env * cc.invt, 1.0f);                                 \
        py[u] = v * (sqrtf(sqrtf(m)) * __builtin_amdgcn_rcpf(m));             \
      }                                                                       \
      py += U;
    for (int k = 0; k < 4; ++k) {
      #pragma unroll
      for (int u = 0; u < U; ++u) b1[u] = p[(size_t)u * NCC];
      p += (size_t)U * NCC;
      CP_OUT(b0)
      #pragma unroll
      for (int u = 0; u < U; ++u) b0[u] = p[(size_t)u * NCC];
      p += (size_t)U * NCC;
      CP_OUT(b1)
    }
    #pragma unroll
    for (int u = 0; u < U; ++u) b1[u] = p[(size_t)u * NCC];
    CP_OUT(b0)
    CP_OUT(b1)
  }
}

// ===== Comb: y[n] = x[n] + fb*y[n-d]; phase-parallel chains =====
__global__ __launch_bounds__(256) void comb_kernel(const float* __restrict__ xin,
                                                   float* __restrict__ acc,
                                                   int d, int J, int first) {
  int tid = blockIdx.x * 256 + threadIdx.x;
  int total = 4 * d * J;
  if (tid >= total) return;
  int rch = tid / (d * J);
  int rem = tid - rch * (d * J);
  int j = rem / d;
  int p = rem - j * d;
  const float* xi = xin + (size_t)(4 + rch) * NS;  // comp_out channels 4..7
  float* ao = acc + (size_t)rch * NS;
  int K = (NS - p + d - 1) / d;
  int kstart = j * CB;
  if (kstart >= K) return;
  int kend = kstart + CB; if (kend > K) kend = K;
  float yv = 0.f;
  int k = (j == 0) ? 0 : (kstart - RVW);
  int n = k * d + p;
  if (j != 0) {
    #pragma unroll 8
    for (; k < kstart; ++k, n += d) yv = fmaf(FBC, yv, xi[n]);
  }
  if (first) {
    #pragma unroll 8
    for (; k < kend; ++k, n += d) { yv = fmaf(FBC, yv, xi[n]); ao[n] = yv; }
  } else {
    #pragma unroll 8
    for (; k < kend; ++k, n += d) { yv = fmaf(FBC, yv, xi[n]); ao[n] += yv; }
  }
}

// ===== Allpass: y[n<d]=0; y[n] = -fb*u[n] + u[n-d] + fb*y[n-d] =====
__global__ __launch_bounds__(256) void allpass_kernel(const float* __restrict__ xin,
                                                      float* __restrict__ yout,
                                                      int d, int J, float inscale) {
  int tid = blockIdx.x * 256 + threadIdx.x;
  int total = 4 * d * J;
  if (tid >= total) return;
  int rch = tid / (d * J);
  int rem = tid - rch * (d * J);
  int j = rem / d;
  int p = rem - j * d;
  const float* xi = xin + (size_t)rch * NS;
  float* yo = yout + (size_t)rch * NS;
  int K = (NS - p + d - 1) / d;
  int kstart = j * CB;
  if (kstart >= K) return;
  int kend = kstart + CB; if (kend > K) kend = K;
  float yv = 0.f;
  int k;
  if (j == 0) { yo[p] = 0.f; k = 1; }
  else        { k = kstart - RVW; }
  int n = k * d + p;
  if (j != 0) {
    #pragma unroll 8
    for (; k < kstart; ++k, n += d) {
      float u  = inscale * xi[n];
      float up = inscale * xi[n - d];
      yv = fmaf(FBC, yv, fmaf(-FBC, u, up));
    }
  }
  #pragma unroll 8
  for (; k < kend; ++k, n += d) {
    float u  = inscale * xi[n];
    float up = inscale * xi[n - d];
    yv = fmaf(FBC, yv, fmaf(-FBC, u, up));
    yo[n] = yv;
  }
}

// ===== Pan/volume gains =====
__global__ void gains_kernel(const float* __restrict__ vol, const float* __restrict__ pan,
                             float* __restrict__ g) {
  int t = threadIdx.x;
  if (t < 4) {
    float angle = (pan[t] + 1.0f) * 0.25f * 3.14159265358979323846f;
    g[2 * t]     = vol[t] * cosf(angle);
    g[2 * t + 1] = vol[t] * sinf(angle);
  }
}

// ===== Final mix =====
__global__ __launch_bounds__(256) void mix_kernel(const float* __restrict__ cp,
                                                  const float* __restrict__ wet,
                                                  const float* __restrict__ g,
                                                  float* __restrict__ out) {
  int i = blockIdx.x * 256 + threadIdx.x;
  if (i >= NS / 4) return;
  size_t n = (size_t)i * 4;
  float g0 = g[0], g1 = g[1], g2 = g[2], g3 = g[3];
  float g4 = g[4], g5 = g[5], g6 = g[6], g7 = g[7];
  const float CEIL = 0.89125093813374556f;
  float4 t0l = *(const float4*)(cp + 0 * (size_t)NS + n);
  float4 t0r = *(const float4*)(cp + 1 * (size_t)NS + n);
  float4 t1l = *(const float4*)(cp + 2 * (size_t)NS + n);
  float4 t1r = *(const float4*)(cp + 3 * (size_t)NS + n);
  float4 t2l = *(const float4*)(cp + 4 * (size_t)NS + n);
  float4 t2r = *(const float4*)(cp + 5 * (size_t)NS + n);
  float4 t3l = *(const float4*)(cp + 6 * (size_t)NS + n);
  float4 t3r = *(const float4*)(cp + 7 * (size_t)NS + n);
  float4 w2l = *(const float4*)(wet + 0 * (size_t)NS + n);
  float4 w2r = *(const float4*)(wet + 1 * (size_t)NS + n);
  float4 w3l = *(const float4*)(wet + 2 * (size_t)NS + n);
  float4 w3r = *(const float4*)(wet + 3 * (size_t)NS + n);
  float4 outl, outr;
  float* pl = &outl.x; float* pr = &outr.x;
  const float* a0 = &t0l.x; const float* a1 = &t0r.x;
  const float* a2 = &t1l.x; const float* a3 = &t1r.x;
  const float* a4 = &t2l.x; const float* a5 = &t2r.x;
  const float* a6 = &t3l.x; const float* a7 = &t3r.x;
  const float* b4 = &w2l.x; const float* b5 = &w2r.x;
  const float* b6 = &w3l.x; const float* b7 = &w3r.x;
  #pragma unroll
  for (int cc = 0; cc < 4; ++cc) {
    float x4 = 0.7f * a4[cc] + 0.3f * b4[cc];
    float x5 = 0.7f * a5[cc] + 0.3f * b5[cc];
    float x6 = 0.7f * a6[cc] + 0.3f * b6[cc];
    float x7 = 0.7f * a7[cc] + 0.3f * b7[cc];
    float Lv = g0 * a0[cc] + g2 * a2[cc] + g4 * x4 + g6 * x6;
    float Rv = g1 * a1[cc] + g3 * a3[cc] + g5 * x5 + g7 * x7;
    pl[cc] = fminf(fmaxf(Lv, -CEIL), CEIL);
    pr[cc] = fminf(fmaxf(Rv, -CEIL), CEIL);
  }
  *(float4*)(out + n) = outl;
  *(float4*)(out + (size_t)NS + n) = outr;
}

// ---------------- Host side ----------------
static void peak_coefs(double f, double gdb, double q, float* o) {
  double A  = pow(10.0, gdb / 40.0);
  double w0 = 2.0 * M_PI * f / 48000.0;
  double al = sin(w0) / (2.0 * q);
  double a0 = 1.0 + al / A;
  o[0] = (float)((1.0 + al * A) / a0);
  o[1] = (float)(-2.0 * cos(w0) / a0);
  o[2] = (float)((1.0 - al * A) / a0);
  o[3] = (float)(-2.0 * cos(w0) / a0);
  o[4] = (float)((1.0 - al / A) / a0);
}

extern "C" void kernel_launch(void* const* d_in, const int* in_sizes, int n_in,
                              void* d_out, int out_size, void* d_ws, size_t ws_size,
                              hipStream_t stream) {
  const float* tracks = (const float*)d_in[0];
  const float* vols   = (const float*)d_in[1];
  const float* pans   = (const float*)d_in[2];
  float* out = (float*)d_out;
  float* w = (float*)d_ws;
  // ws layout (floats):
  //  [0,8N)   : XT (transposed input) -> reused as comp output Y (natural)
  //  [8N,16N) : ET (chunk-major EQ out) -> after comp: comb acc [8N,12N),
  //             ap240 out [12N,16N), ap81 out back to [8N,12N) = wet
  //  gains at [12N,12N+8) after ap81
  float* XT    = w;
  float* ET    = w + (size_t)8 * NS;
  float* cpbuf = w;
  float* combb = w + (size_t)8 * NS;
  float* apb   = w + (size_t)12 * NS;
  float* wet2  = w + (size_t)8 * NS;
  float* gbuf  = w + (size_t)12 * NS;

  Coefs cf;
  const float ident[5] = {1.f, 0.f, 0.f, 0.f, 0.f};
  const double P[4][3][3] = {
    {{300, -3, 0.7}, {3000, 3, 1.0}, {8000, 2, 0.7}},
    {{80, 2, 0.7},   {5000, 1, 1.0}, {0, 0, 0}},
    {{200, -2, 0.7}, {6000, -1, 0.7}, {0, 0, 0}},
    {{1000, 2, 1.0}, {0, 0, 0},      {0, 0, 0}},
  };
  const int nb[4] = {3, 2, 2, 1};
  for (int t = 0; t < 4; ++t)
    for (int s = 0; s < 3; ++s) {
      if (s < nb[t]) peak_coefs(P[t][s][0], P[t][s][1], P[t][s][2], cf.c[s][t]);
      else for (int q = 0; q < 5; ++q) cf.c[s][t][q] = ident[q];
    }

  CompC cc;
  double atk = exp(-1.0 / 480.0), rel = exp(-1.0 / 4800.0);
  cc.atk  = (float)atk;  cc.rel  = (float)rel;
  cc.oatk = (float)(1.0 - atk); cc.orel = (float)(1.0 - rel);
  cc.invt = (float)(1.0 / (pow(10.0, -18.0 / 20.0) + 1e-8));

  hipLaunchKernelGGL(transpose_in, dim3(8 * 15 * 375), dim3(256), 0, stream,
                     tracks, XT);
  hipLaunchKernelGGL(eq_kernel, dim3(8 * CHB), dim3(64), 0, stream,
                     XT, ET, cf);
  hipLaunchKernelGGL(comp_kernel, dim3(8 * CHB), dim3(64), 0, stream,
                     ET, cpbuf, cc);

  const int combd[4] = {1440, 1627, 1828, 2030};
  for (int i = 0; i < 4; ++i) {
    int d = combd[i];
    int K = (NS + d - 1) / d;
    int J = (K + CB - 1) / CB;
    int total = 4 * d * J;
    hipLaunchKernelGGL(comb_kernel, dim3((total + 255) / 256), dim3(256), 0, stream,
                       cpbuf, combb, d, J, (i == 0) ? 1 : 0);
  }
  {
    int d = 240, K = (NS + d - 1) / d, J = (K + CB - 1) / CB, total = 4 * d * J;
    hipLaunchKernelGGL(allpass_kernel, dim3((total + 255) / 256), dim3(256), 0, stream,
                       combb, apb, d, J, 0.25f);
  }
  {
    int d = 81, K = (NS + d - 1) / d, J = (K + CB - 1) / CB, total = 4 * d * J;
    hipLaunchKernelGGL(allpass_kernel, dim3((total + 255) / 256), dim3(256), 0, stream,
                       apb, wet2, d, J, 1.0f);
  }
  hipLaunchKernelGGL(gains_kernel, dim3(1), dim3(64), 0, stream, vols, pans, gbuf);
  hipLaunchKernelGGL(mix_kernel, dim3((NS / 4 + 255) / 256), dim3(256), 0, stream,
                     cpbuf, wet2, gbuf, out);
}

// Round 5
// 722.437 us; speedup vs baseline: 1.6400x; 1.6400x over previous
//
#include <hip/hip_runtime.h>
#include <math.h>

#define NS  1440000
#define LC  240         // chunk length
#define NCC 6000        // chunks per channel; LC*NCC == NS
#define CHB 94          // ceil(NCC/64) chunk-blocks per channel
#define CPW 47          // comp warm chunks = 11280 samples (decay ~e^-8.7)
#define EQW 9           // eq warm chunks = 2160 samples (worst pole^2160 ~ 5e-7)
#define CWIN (64 + CPW - 1)       // 110 warm window columns
#define EWIN (64 + EQW - 1)       // 72 warm window columns
#define WPC 121         // LDS words per column (120 data + 1 pad; stride 121%32=25 -> conflict-free)
#define U   24          // prefetch strip for output passes; 240 = 2*U*5

// ---- Reverb chain chunking ----
#define CB  128        // chain-steps per thread
#define RVW 40         // chain warm-up steps (0.6^40 ~ 1e-9)
#define FBC 0.6f       // feedback = 0.3 + 0.5*0.6

struct Coefs { float c[3][4][5]; };            // [stage][track][b0,b1,b2,a1,a2]
struct CompC { float atk, rel, rho, invt2; };  // rho=orel/oatk, invt2=oatk*invt

// ===== Tiled transpose: x[ch][c*LC+s] -> XT[ch][s*NCC+c] =====
__global__ __launch_bounds__(256) void transpose_in(const float* __restrict__ x,
                                                    float* __restrict__ XT) {
  __shared__ float t[16][17];
  int b = blockIdx.x;
  int ch = b / (15 * 375);
  int r  = b % (15 * 375);
  int it = r / 375, jt = r % 375;      // s-tile, c-tile
  int tx = threadIdx.x & 15, ty = threadIdx.x >> 4;
  int s0 = it * 16, c0 = jt * 16;
  t[ty][tx] = x[(size_t)ch * NS + (size_t)(c0 + ty) * LC + (s0 + tx)];
  __syncthreads();
  XT[(size_t)ch * NS + (size_t)(s0 + ty) * NCC + (c0 + tx)] = t[tx][ty];
}

__device__ inline unsigned int f32_to_bf16_rtne(float v) {
  unsigned int b = __float_as_uint(v);
  return (b + 0x7fffu + ((b >> 16) & 1u)) >> 16;
}

// ===== EQ: lockstep-diagonal warm-up, strip-prefetched from LDS =====
#define EQ_STEP(VV)                                                        \
  {                                                                        \
    float v = (VV);                                                        \
    _Pragma("unroll")                                                      \
    for (int st = 0; st < 3; ++st) {                                       \
      float ya = fmaf(c[st][0], v, z[st][0]);                              \
      z[st][0] = fmaf(c[st][1], v, z[st][1]) - c[st][3] * ya;              \
      z[st][1] = fmaf(c[st][2], v, -(c[st][4] * ya));                      \
      v = ya;                                                              \
    }                                                                      \
    vout = v;                                                              \
  }

#define EQ_W40(B)                                                          \
  _Pragma("unroll")                                                        \
  for (int u = 0; u < 20; ++u) {                                           \
    unsigned int wv = (B)[u];                                              \
    float lo = __uint_as_float(wv << 16);                                  \
    float hi = __uint_as_float(wv & 0xffff0000u);                          \
    EQ_STEP(lo);                                                           \
    EQ_STEP(hi);                                                           \
  }

__global__ __launch_bounds__(64) void eq_kernel(const float* __restrict__ XT,
                                                float* __restrict__ ET, Coefs cf) {
  __shared__ unsigned int lds[(EWIN + 1) * WPC];   // +1 pad column for prefetch overrun
  int blk = blockIdx.x;
  int ch = blk / CHB, cb = blk % CHB;
  int C0 = cb * 64;
  int lane = threadIdx.x;
  int tr = ch >> 1;
  float c[3][5];
  #pragma unroll
  for (int st = 0; st < 3; ++st)
    #pragma unroll
    for (int q = 0; q < 5; ++q) c[st][q] = cf.c[st][tr][q];
  const float* X = XT + (size_t)ch * NS;
  // ---- cooperative window fill (cols [C0-EQW, C0+63), bf16) ----
  for (int e = lane; e < EWIN * LC; e += 64) {
    int s = e / EWIN, cr = e - s * EWIN;
    int cg = C0 - EQW + cr;
    float v = (cg >= 0 && cg < NCC) ? X[(size_t)s * NCC + cg] : 0.f;
    ((unsigned short*)lds)[cr * (2 * WPC) + s] = (unsigned short)f32_to_bf16_rtne(v);
  }
  __syncthreads();
  float z[3][2] = {{0,0},{0,0},{0,0}};
  float vout;
  // ---- warm: column (lane+t), 6 strips of 20 words, double-buffered ----
  {
    unsigned int b0[20], b1[20];
    const unsigned int* pc = lds + lane * WPC;
    #pragma unroll
    for (int u = 0; u < 20; ++u) b0[u] = pc[u];
    for (int t = 0; t < EQW; ++t) {
      #pragma unroll
      for (int u = 0; u < 20; ++u) b1[u] = pc[20 + u];
      EQ_W40(b0)
      #pragma unroll
      for (int u = 0; u < 20; ++u) b0[u] = pc[40 + u];
      EQ_W40(b1)
      #pragma unroll
      for (int u = 0; u < 20; ++u) b1[u] = pc[60 + u];
      EQ_W40(b0)
      #pragma unroll
      for (int u = 0; u < 20; ++u) b0[u] = pc[80 + u];
      EQ_W40(b1)
      #pragma unroll
      for (int u = 0; u < 20; ++u) b1[u] = pc[100 + u];
      EQ_W40(b0)
      pc += WPC;
      #pragma unroll
      for (int u = 0; u < 20; ++u) b0[u] = pc[u];   // strip0 of next col (pad col at end)
      EQ_W40(b1)
    }
  }
  (void)vout;
  // ---- output chunk: exact f32 reads (coalesced), coalesced stores ----
  int cg = C0 + lane;
  if (cg < NCC) {
    const float* p = X + cg;
    float* q = ET + (size_t)ch * NS + cg;
    float b0[U], b1[U];
    #pragma unroll
    for (int u = 0; u < U; ++u) b0[u] = p[(size_t)u * NCC];
    p += (size_t)U * NCC;
    for (int k = 0; k < 4; ++k) {
      #pragma unroll
      for (int u = 0; u < U; ++u) b1[u] = p[(size_t)u * NCC];
      p += (size_t)U * NCC;
      #pragma unroll
      for (int u = 0; u < U; ++u) { EQ_STEP(b0[u]); q[(size_t)u * NCC] = vout; }
      q += (size_t)U * NCC;
      #pragma unroll
      for (int u = 0; u < U; ++u) b0[u] = p[(size_t)u * NCC];
      p += (size_t)U * NCC;
      #pragma unroll
      for (int u = 0; u < U; ++u) { EQ_STEP(b1[u]); q[(size_t)u * NCC] = vout; }
      q += (size_t)U * NCC;
    }
    #pragma unroll
    for (int u = 0; u < U; ++u) b1[u] = p[(size_t)u * NCC];
    #pragma unroll
    for (int u = 0; u < U; ++u) { EQ_STEP(b0[u]); q[(size_t)u * NCC] = vout; }
    q += (size_t)U * NCC;
    #pragma unroll
    for (int u = 0; u < U; ++u) { EQ_STEP(b1[u]); q[(size_t)u * NCC] = vout; }
  }
}

// ===== Compressor: E = env/oatk domain; E' = max(atk*E + v, rel*E + rho*v) =====
#define CP_W40(B)                                                          \
  _Pragma("unroll")                                                        \
  for (int u = 0; u < 20; ++u) {                                           \
    unsigned int wv = (B)[u];                                              \
    float lo = __uint_as_float(wv << 16);                                  \
    float hi = __uint_as_float(wv & 0xffff0000u);                          \
    E = fmaxf(fmaf(cc.atk, E, lo), fmaf(cc.rel, E, cc.rho * lo));          \
    E = fmaxf(fmaf(cc.atk, E, hi), fmaf(cc.rel, E, cc.rho * hi));          \
  }

__global__ __launch_bounds__(64) void comp_kernel(const float* __restrict__ ET,
                                                  float* __restrict__ Y, CompC cc) {
  __shared__ unsigned int lds[(CWIN + 1) * WPC];   // 111*121*4B = 53.7 KB -> 3 blocks/CU
  int blk = blockIdx.x;
  int ch = blk / CHB, cb = blk % CHB;
  int C0 = cb * 64;
  int lane = threadIdx.x;
  const float* E_ = ET + (size_t)ch * NS;
  // ---- cooperative window fill (cols [C0-CPW, C0+63), |x| as bf16) ----
  for (int e = lane; e < CWIN * LC; e += 64) {
    int s = e / CWIN, cr = e - s * CWIN;
    int cg = C0 - CPW + cr;
    float v = (cg >= 0 && cg < NCC) ? E_[(size_t)s * NCC + cg] : 0.f;
    unsigned int b = __float_as_uint(v) & 0x7fffffffu;   // abs
    b = (b + 0x7fffu + ((b >> 16) & 1u)) >> 16;
    ((unsigned short*)lds)[cr * (2 * WPC) + s] = (unsigned short)b;
  }
  __syncthreads();
  float E = 0.f;   // env / oatk
  // ---- warm: column (lane+t), 6 strips of 20 words, double-buffered ----
  {
    unsigned int b0[20], b1[20];
    const unsigned int* pc = lds + lane * WPC;
    #pragma unroll
    for (int u = 0; u < 20; ++u) b0[u] = pc[u];
    for (int t = 0; t < CPW; ++t) {
      #pragma unroll
      for (int u = 0; u < 20; ++u) b1[u] = pc[20 + u];
      CP_W40(b0)
      #pragma unroll
      for (int u = 0; u < 20; ++u) b0[u] = pc[40 + u];
      CP_W40(b1)
      #pragma unroll
      for (int u = 0; u < 20; ++u) b1[u] = pc[60 + u];
      CP_W40(b0)
      #pragma unroll
      for (int u = 0; u < 20; ++u) b0[u] = pc[80 + u];
      CP_W40(b1)
      #pragma unroll
      for (int u = 0; u < 20; ++u) b1[u] = pc[100 + u];
      CP_W40(b0)
      pc += WPC;
      #pragma unroll
      for (int u = 0; u < 20; ++u) b0[u] = pc[u];
      CP_W40(b1)
    }
  }
  // ---- output chunk: exact f32 reads (coalesced), natural-layout writes ----
  int cg = C0 + lane;
  if (cg < NCC) {
    const float* p = E_ + cg;
    float* py = Y + (size_t)ch * NS + (size_t)cg * LC;
    float b0[U], b1[U];
    #pragma unroll
    for (int u = 0; u < U; ++u) b0[u] = p[(size_t)u * NCC];
    p += (size_t)U * NCC;
    #define CP_OUT(BUF)                                                       \
      _Pragma("unroll")                                                       \
      for (int u = 0; u < U; ++u) {                                           \
        float v = BUF[u];                                                     \
        float lvl = fabsf(v);                                                 \
        E = fmaxf(fmaf(cc.atk, E, lvl), fmaf(cc.rel, E, cc.rho * lvl));       \
        float m = fmaxf(E * cc.invt2, 1.0f);                                  \
        py[u] = v * (sqrtf(sqrtf(m)) * __builtin_amdgcn_rcpf(m));             \
      }                                                                       \
      py += U;
    for (int k = 0; k < 4; ++k) {
      #pragma unroll
      for (int u = 0; u < U; ++u) b1[u] = p[(size_t)u * NCC];
      p += (size_t)U * NCC;
      CP_OUT(b0)
      #pragma unroll
      for (int u = 0; u < U; ++u) b0[u] = p[(size_t)u * NCC];
      p += (size_t)U * NCC;
      CP_OUT(b1)
    }
    #pragma unroll
    for (int u = 0; u < U; ++u) b1[u] = p[(size_t)u * NCC];
    CP_OUT(b0)
    CP_OUT(b1)
  }
}

// ===== Comb: y[n] = x[n] + fb*y[n-d]; phase-parallel chains =====
__global__ __launch_bounds__(256) void comb_kernel(const float* __restrict__ xin,
                                                   float* __restrict__ acc,
                                                   int d, int J, int first) {
  int tid = blockIdx.x * 256 + threadIdx.x;
  int total = 4 * d * J;
  if (tid >= total) return;
  int rch = tid / (d * J);
  int rem = tid - rch * (d * J);
  int j = rem / d;
  int p = rem - j * d;
  const float* xi = xin + (size_t)(4 + rch) * NS;  // comp_out channels 4..7
  float* ao = acc + (size_t)rch * NS;
  int K = (NS - p + d - 1) / d;
  int kstart = j * CB;
  if (kstart >= K) return;
  int kend = kstart + CB; if (kend > K) kend = K;
  float yv = 0.f;
  int k = (j == 0) ? 0 : (kstart - RVW);
  int n = k * d + p;
  if (j != 0) {
    #pragma unroll 8
    for (; k < kstart; ++k, n += d) yv = fmaf(FBC, yv, xi[n]);
  }
  if (first) {
    #pragma unroll 8
    for (; k < kend; ++k, n += d) { yv = fmaf(FBC, yv, xi[n]); ao[n] = yv; }
  } else {
    #pragma unroll 8
    for (; k < kend; ++k, n += d) { yv = fmaf(FBC, yv, xi[n]); ao[n] += yv; }
  }
}

// ===== Allpass: y[n<d]=0; y[n] = -fb*u[n] + u[n-d] + fb*y[n-d] =====
__global__ __launch_bounds__(256) void allpass_kernel(const float* __restrict__ xin,
                                                      float* __restrict__ yout,
                                                      int d, int J, float inscale) {
  int tid = blockIdx.x * 256 + threadIdx.x;
  int total = 4 * d * J;
  if (tid >= total) return;
  int rch = tid / (d * J);
  int rem = tid - rch * (d * J);
  int j = rem / d;
  int p = rem - j * d;
  const float* xi = xin + (size_t)rch * NS;
  float* yo = yout + (size_t)rch * NS;
  int K = (NS - p + d - 1) / d;
  int kstart = j * CB;
  if (kstart >= K) return;
  int kend = kstart + CB; if (kend > K) kend = K;
  float yv = 0.f;
  int k;
  if (j == 0) { yo[p] = 0.f; k = 1; }
  else        { k = kstart - RVW; }
  int n = k * d + p;
  if (j != 0) {
    #pragma unroll 8
    for (; k < kstart; ++k, n += d) {
      float u  = inscale * xi[n];
      float up = inscale * xi[n - d];
      yv = fmaf(FBC, yv, fmaf(-FBC, u, up));
    }
  }
  #pragma unroll 8
  for (; k < kend; ++k, n += d) {
    float u  = inscale * xi[n];
    float up = inscale * xi[n - d];
    yv = fmaf(FBC, yv, fmaf(-FBC, u, up));
    yo[n] = yv;
  }
}

// ===== Pan/volume gains =====
__global__ void gains_kernel(const float* __restrict__ vol, const float* __restrict__ pan,
                             float* __restrict__ g) {
  int t = threadIdx.x;
  if (t < 4) {
    float angle = (pan[t] + 1.0f) * 0.25f * 3.14159265358979323846f;
    g[2 * t]     = vol[t] * cosf(angle);
    g[2 * t + 1] = vol[t] * sinf(angle);
  }
}

// ===== Final mix =====
__global__ __launch_bounds__(256) void mix_kernel(const float* __restrict__ cp,
                                                  const float* __restrict__ wet,
                                                  const float* __restrict__ g,
                                                  float* __restrict__ out) {
  int i = blockIdx.x * 256 + threadIdx.x;
  if (i >= NS / 4) return;
  size_t n = (size_t)i * 4;
  float g0 = g[0], g1 = g[1], g2 = g[2], g3 = g[3];
  float g4 = g[4], g5 = g[5], g6 = g[6], g7 = g[7];
  const float CEIL = 0.89125093813374556f;
  float4 t0l = *(const float4*)(cp + 0 * (size_t)NS + n);
  float4 t0r = *(const float4*)(cp + 1 * (size_t)NS + n);
  float4 t1l = *(const float4*)(cp + 2 * (size_t)NS + n);
  float4 t1r = *(const float4*)(cp + 3 * (size_t)NS + n);
  float4 t2l = *(const float4*)(cp + 4 * (size_t)NS + n);
  float4 t2r = *(const float4*)(cp + 5 * (size_t)NS + n);
  float4 t3l = *(const float4*)(cp + 6 * (size_t)NS + n);
  float4 t3r = *(const float4*)(cp + 7 * (size_t)NS + n);
  float4 w2l = *(const float4*)(wet + 0 * (size_t)NS + n);
  float4 w2r = *(const float4*)(wet + 1 * (size_t)NS + n);
  float4 w3l = *(const float4*)(wet + 2 * (size_t)NS + n);
  float4 w3r = *(const float4*)(wet + 3 * (size_t)NS + n);
  float4 outl, outr;
  float* pl = &outl.x; float* pr = &outr.x;
  const float* a0 = &t0l.x; const float* a1 = &t0r.x;
  const float* a2 = &t1l.x; const float* a3 = &t1r.x;
  const float* a4 = &t2l.x; const float* a5 = &t2r.x;
  const float* a6 = &t3l.x; const float* a7 = &t3r.x;
  const float* b4 = &w2l.x; const float* b5 = &w2r.x;
  const float* b6 = &w3l.x; const float* b7 = &w3r.x;
  #pragma unroll
  for (int cc = 0; cc < 4; ++cc) {
    float x4 = 0.7f * a4[cc] + 0.3f * b4[cc];
    float x5 = 0.7f * a5[cc] + 0.3f * b5[cc];
    float x6 = 0.7f * a6[cc] + 0.3f * b6[cc];
    float x7 = 0.7f * a7[cc] + 0.3f * b7[cc];
    float Lv = g0 * a0[cc] + g2 * a2[cc] + g4 * x4 + g6 * x6;
    float Rv = g1 * a1[cc] + g3 * a3[cc] + g5 * x5 + g7 * x7;
    pl[cc] = fminf(fmaxf(Lv, -CEIL), CEIL);
    pr[cc] = fminf(fmaxf(Rv, -CEIL), CEIL);
  }
  *(float4*)(out + n) = outl;
  *(float4*)(out + (size_t)NS + n) = outr;
}

// ---------------- Host side ----------------
static void peak_coefs(double f, double gdb, double q, float* o) {
  double A  = pow(10.0, gdb / 40.0);
  double w0 = 2.0 * M_PI * f / 48000.0;
  double al = sin(w0) / (2.0 * q);
  double a0 = 1.0 + al / A;
  o[0] = (float)((1.0 + al * A) / a0);
  o[1] = (float)(-2.0 * cos(w0) / a0);
  o[2] = (float)((1.0 - al * A) / a0);
  o[3] = (float)(-2.0 * cos(w0) / a0);
  o[4] = (float)((1.0 - al / A) / a0);
}

extern "C" void kernel_launch(void* const* d_in, const int* in_sizes, int n_in,
                              void* d_out, int out_size, void* d_ws, size_t ws_size,
                              hipStream_t stream) {
  const float* tracks = (const float*)d_in[0];
  const float* vols   = (const float*)d_in[1];
  const float* pans   = (const float*)d_in[2];
  float* out = (float*)d_out;
  float* w = (float*)d_ws;
  // ws layout (floats):
  //  [0,8N)   : XT (transposed input) -> reused as comp output Y (natural)
  //  [8N,16N) : ET (chunk-major EQ out) -> after comp: comb acc [8N,12N),
  //             ap240 out [12N,16N), ap81 out back to [8N,12N) = wet
  //  gains at [12N,12N+8) after ap81
  float* XT    = w;
  float* ET    = w + (size_t)8 * NS;
  float* cpbuf = w;
  float* combb = w + (size_t)8 * NS;
  float* apb   = w + (size_t)12 * NS;
  float* wet2  = w + (size_t)8 * NS;
  float* gbuf  = w + (size_t)12 * NS;

  Coefs cf;
  const float ident[5] = {1.f, 0.f, 0.f, 0.f, 0.f};
  const double P[4][3][3] = {
    {{300, -3, 0.7}, {3000, 3, 1.0}, {8000, 2, 0.7}},
    {{80, 2, 0.7},   {5000, 1, 1.0}, {0, 0, 0}},
    {{200, -2, 0.7}, {6000, -1, 0.7}, {0, 0, 0}},
    {{1000, 2, 1.0}, {0, 0, 0},      {0, 0, 0}},
  };
  const int nb[4] = {3, 2, 2, 1};
  for (int t = 0; t < 4; ++t)
    for (int s = 0; s < 3; ++s) {
      if (s < nb[t]) peak_coefs(P[t][s][0], P[t][s][1], P[t][s][2], cf.c[s][t]);
      else for (int q = 0; q < 5; ++q) cf.c[s][t][q] = ident[q];
    }

  CompC cc;
  double atk = exp(-1.0 / 480.0), rel = exp(-1.0 / 4800.0);
  double oatk = 1.0 - atk, orel = 1.0 - rel;
  double invt = 1.0 / (pow(10.0, -18.0 / 20.0) + 1e-8);
  cc.atk   = (float)atk;
  cc.rel   = (float)rel;
  cc.rho   = (float)(orel / oatk);
  cc.invt2 = (float)(oatk * invt);

  hipLaunchKernelGGL(transpose_in, dim3(8 * 15 * 375), dim3(256), 0, stream,
                     tracks, XT);
  hipLaunchKernelGGL(eq_kernel, dim3(8 * CHB), dim3(64), 0, stream,
                     XT, ET, cf);
  hipLaunchKernelGGL(comp_kernel, dim3(8 * CHB), dim3(64), 0, stream,
                     ET, cpbuf, cc);

  const int combd[4] = {1440, 1627, 1828, 2030};
  for (int i = 0; i < 4; ++i) {
    int d = combd[i];
    int K = (NS + d - 1) / d;
    int J = (K + CB - 1) / CB;
    int total = 4 * d * J;
    hipLaunchKernelGGL(comb_kernel, dim3((total + 255) / 256), dim3(256), 0, stream,
                       cpbuf, combb, d, J, (i == 0) ? 1 : 0);
  }
  {
    int d = 240, K = (NS + d - 1) / d, J = (K + CB - 1) / CB, total = 4 * d * J;
    hipLaunchKernelGGL(allpass_kernel, dim3((total + 255) / 256), dim3(256), 0, stream,
                       combb, apb, d, J, 0.25f);
  }
  {
    int d = 81, K = (NS + d - 1) / d, J = (K + CB - 1) / CB, total = 4 * d * J;
    hipLaunchKernelGGL(allpass_kernel, dim3((total + 255) / 256), dim3(256), 0, stream,
                       apb, wet2, d, J, 1.0f);
  }
  hipLaunchKernelGGL(gains_kernel, dim3(1), dim3(64), 0, stream, vols, pans, gbuf);
  hipLaunchKernelGGL(mix_kernel, dim3((NS / 4 + 255) / 256), dim3(256), 0, stream,
                     cpbuf, wet2, gbuf, out);
}

// Round 7
// 534.481 us; speedup vs baseline: 2.2167x; 1.3517x over previous
//
#include <hip/hip_runtime.h>
#include <math.h>

#define NS  1440000
#define LC  240         // chunk length
#define NCC 6000        // chunks per channel; LC*NCC == NS
#define CHB 94          // ceil(NCC/64) chunk-blocks per channel
#define CPW 47          // comp warm chunks = 11280 samples (proven)
#define EQW 6           // eq warm chunks = 1440 samples (worst pole^1440 ~ 6.7e-5)
#define CWIN (64 + CPW - 1)       // 110 warm window columns
#define EWIN (64 + EQW - 1)       // 69 warm window columns
#define WPC 121         // LDS words per column (120 data + 1 pad; 121%32=25 -> conflict-free)
#define U   24          // prefetch strip for output passes; 240 = 2*U*5

// ---- Reverb chain chunking ----
#define CB  64         // chain-steps per thread (64 -> ~1440 waves/launch)
#define RVW 40         // chain warm-up steps (0.6^40 ~ 1e-9)
#define FBC 0.6f       // feedback = 0.3 + 0.5*0.6

struct Coefs { float c[3][4][5]; };            // [stage][track][b0,b1,b2,a1,a2]
struct CompC { float atk, rel, rho, invt2; };  // rho=orel/oatk, invt2=oatk*invt

// ===== Tiled transpose: x[ch][c*LC+s] -> XT[ch][s*NCC+c] =====
__global__ __launch_bounds__(256) void transpose_in(const float* __restrict__ x,
                                                    float* __restrict__ XT) {
  __shared__ float t[16][17];
  int b = blockIdx.x;
  int ch = b / (15 * 375);
  int r  = b % (15 * 375);
  int it = r / 375, jt = r % 375;
  int tx = threadIdx.x & 15, ty = threadIdx.x >> 4;
  int s0 = it * 16, c0 = jt * 16;
  t[ty][tx] = x[(size_t)ch * NS + (size_t)(c0 + ty) * LC + (s0 + tx)];
  __syncthreads();
  XT[(size_t)ch * NS + (size_t)(s0 + ty) * NCC + (c0 + tx)] = t[tx][ty];
}

__device__ inline unsigned int f32_to_bf16_rtne(float v) {
  unsigned int b = __float_as_uint(v);
  return (b + 0x7fffu + ((b >> 16) & 1u)) >> 16;
}

// ===== EQ: stage-count-templated body; lockstep-diagonal warm-up from LDS =====
#define EQ_STEPT(VV)                                                       \
  {                                                                        \
    float v = (VV);                                                        \
    _Pragma("unroll")                                                      \
    for (int st = 0; st < NST; ++st) {                                     \
      float ya = fmaf(c[st][0], v, z[st][0]);                              \
      z[st][0] = fmaf(c[st][1], v, z[st][1]) - c[st][3] * ya;              \
      z[st][1] = fmaf(c[st][2], v, -(c[st][4] * ya));                      \
      v = ya;                                                              \
    }                                                                      \
    vout = v;                                                              \
  }

#define EQ_W40T(B)                                                         \
  _Pragma("unroll")                                                        \
  for (int u = 0; u < 20; ++u) {                                           \
    unsigned int wv = (B)[u];                                              \
    float lo = __uint_as_float(wv << 16);                                  \
    float hi = __uint_as_float(wv & 0xffff0000u);                          \
    EQ_STEPT(lo);                                                          \
    EQ_STEPT(hi);                                                          \
  }

template<int NST>
__device__ __forceinline__ void eq_body(const float* __restrict__ X,
                                        float* __restrict__ E,
                                        const Coefs& cf, int tr,
                                        const unsigned int* __restrict__ lds,
                                        int lane, int C0) {
  float c[NST][5];
  #pragma unroll
  for (int st = 0; st < NST; ++st)
    #pragma unroll
    for (int q = 0; q < 5; ++q) c[st][q] = cf.c[st][tr][q];
  float z[NST][2];
  #pragma unroll
  for (int st = 0; st < NST; ++st) { z[st][0] = 0.f; z[st][1] = 0.f; }
  float vout;
  // ---- warm: column (lane+t), 6 strips of 20 words, double-buffered ----
  {
    unsigned int b0[20], b1[20];
    const unsigned int* pc = lds + lane * WPC;
    #pragma unroll
    for (int u = 0; u < 20; ++u) b0[u] = pc[u];
    for (int t = 0; t < EQW; ++t) {
      #pragma unroll
      for (int u = 0; u < 20; ++u) b1[u] = pc[20 + u];
      EQ_W40T(b0)
      #pragma unroll
      for (int u = 0; u < 20; ++u) b0[u] = pc[40 + u];
      EQ_W40T(b1)
      #pragma unroll
      for (int u = 0; u < 20; ++u) b1[u] = pc[60 + u];
      EQ_W40T(b0)
      #pragma unroll
      for (int u = 0; u < 20; ++u) b0[u] = pc[80 + u];
      EQ_W40T(b1)
      #pragma unroll
      for (int u = 0; u < 20; ++u) b1[u] = pc[100 + u];
      EQ_W40T(b0)
      pc += WPC;
      #pragma unroll
      for (int u = 0; u < 20; ++u) b0[u] = pc[u];   // strip0 of next col (pad col at end)
      EQ_W40T(b1)
    }
  }
  (void)vout;
  // ---- output chunk: exact f32 reads (coalesced), coalesced stores ----
  int cg = C0 + lane;
  if (cg < NCC) {
    const float* p = X + cg;
    float* q = E + cg;
    float b0[U], b1[U];
    #pragma unroll
    for (int u = 0; u < U; ++u) b0[u] = p[(size_t)u * NCC];
    p += (size_t)U * NCC;
    for (int k = 0; k < 4; ++k) {
      #pragma unroll
      for (int u = 0; u < U; ++u) b1[u] = p[(size_t)u * NCC];
      p += (size_t)U * NCC;
      #pragma unroll
      for (int u = 0; u < U; ++u) { EQ_STEPT(b0[u]); q[(size_t)u * NCC] = vout; }
      q += (size_t)U * NCC;
      #pragma unroll
      for (int u = 0; u < U; ++u) b0[u] = p[(size_t)u * NCC];
      p += (size_t)U * NCC;
      #pragma unroll
      for (int u = 0; u < U; ++u) { EQ_STEPT(b1[u]); q[(size_t)u * NCC] = vout; }
      q += (size_t)U * NCC;
    }
    #pragma unroll
    for (int u = 0; u < U; ++u) b1[u] = p[(size_t)u * NCC];
    #pragma unroll
    for (int u = 0; u < U; ++u) { EQ_STEPT(b0[u]); q[(size_t)u * NCC] = vout; }
    q += (size_t)U * NCC;
    #pragma unroll
    for (int u = 0; u < U; ++u) { EQ_STEPT(b1[u]); q[(size_t)u * NCC] = vout; }
  }
}

__global__ __launch_bounds__(64) void eq_kernel(const float* __restrict__ XT,
                                                float* __restrict__ ET, Coefs cf) {
  __shared__ unsigned int lds[(EWIN + 1) * WPC];   // 70*121*4B = 33.9 KB -> 4 blocks/CU
  int blk = blockIdx.x;
  int ch = blk / CHB, cb = blk % CHB;
  int C0 = cb * 64;
  int lane = threadIdx.x;
  int tr = ch >> 1;
  const float* X = XT + (size_t)ch * NS;
  float* E = ET + (size_t)ch * NS;
  // ---- cooperative window fill, batched x4 for MLP ----
  const int TOT = EWIN * LC;
  for (int base = 0; base < TOT; base += 256) {
    float v[4]; int sE[4], crE[4]; bool val[4];
    #pragma unroll
    for (int i = 0; i < 4; ++i) {
      int e = base + i * 64 + lane;
      val[i] = e < TOT;
      int ec = val[i] ? e : 0;
      sE[i] = ec / EWIN; crE[i] = ec - sE[i] * EWIN;
      int cg = C0 - EQW + crE[i];
      v[i] = (val[i] && cg >= 0 && cg < NCC) ? X[(size_t)sE[i] * NCC + cg] : 0.f;
    }
    #pragma unroll
    for (int i = 0; i < 4; ++i)
      if (val[i])
        ((unsigned short*)lds)[crE[i] * (2 * WPC) + sE[i]] =
            (unsigned short)f32_to_bf16_rtne(v[i]);
  }
  __syncthreads();
  if (tr == 0)      eq_body<3>(X, E, cf, tr, lds, lane, C0);
  else if (tr == 3) eq_body<1>(X, E, cf, tr, lds, lane, C0);
  else              eq_body<2>(X, E, cf, tr, lds, lane, C0);
}

// ===== Compressor (R5-proven): E = env/oatk; E' = max(atk*E + v, rel*E + rho*v) =====
#define CP_W40(B)                                                          \
  _Pragma("unroll")                                                        \
  for (int u = 0; u < 20; ++u) {                                           \
    unsigned int wv = (B)[u];                                              \
    float lo = __uint_as_float(wv << 16);                                  \
    float hi = __uint_as_float(wv & 0xffff0000u);                          \
    E = fmaxf(fmaf(cc.atk, E, lo), fmaf(cc.rel, E, cc.rho * lo));          \
    E = fmaxf(fmaf(cc.atk, E, hi), fmaf(cc.rel, E, cc.rho * hi));          \
  }

__global__ __launch_bounds__(64) void comp_kernel(const float* __restrict__ ET,
                                                  float* __restrict__ Y, CompC cc) {
  __shared__ unsigned int lds[(CWIN + 1) * WPC];   // 111*121*4B = 53.7 KB -> 3 blocks/CU
  int blk = blockIdx.x;
  int ch = blk / CHB, cb = blk % CHB;
  int C0 = cb * 64;
  int lane = threadIdx.x;
  const float* E_ = ET + (size_t)ch * NS;
  // ---- cooperative window fill, batched x4 for MLP (|x| as bf16) ----
  const int TOTC = CWIN * LC;
  for (int base = 0; base < TOTC; base += 256) {
    float v[4]; int sE[4], crE[4]; bool val[4];
    #pragma unroll
    for (int i = 0; i < 4; ++i) {
      int e = base + i * 64 + lane;
      val[i] = e < TOTC;
      int ec = val[i] ? e : 0;
      sE[i] = ec / CWIN; crE[i] = ec - sE[i] * CWIN;
      int cg = C0 - CPW + crE[i];
      v[i] = (val[i] && cg >= 0 && cg < NCC) ? E_[(size_t)sE[i] * NCC + cg] : 0.f;
    }
    #pragma unroll
    for (int i = 0; i < 4; ++i)
      if (val[i]) {
        unsigned int b = __float_as_uint(v[i]) & 0x7fffffffu;   // abs
        b = (b + 0x7fffu + ((b >> 16) & 1u)) >> 16;
        ((unsigned short*)lds)[crE[i] * (2 * WPC) + sE[i]] = (unsigned short)b;
      }
  }
  __syncthreads();
  float E = 0.f;   // env / oatk
  // ---- warm: column (lane+t), 6 strips of 20 words, double-buffered ----
  {
    unsigned int b0[20], b1[20];
    const unsigned int* pc = lds + lane * WPC;
    #pragma unroll
    for (int u = 0; u < 20; ++u) b0[u] = pc[u];
    for (int t = 0; t < CPW; ++t) {
      #pragma unroll
      for (int u = 0; u < 20; ++u) b1[u] = pc[20 + u];
      CP_W40(b0)
      #pragma unroll
      for (int u = 0; u < 20; ++u) b0[u] = pc[40 + u];
      CP_W40(b1)
      #pragma unroll
      for (int u = 0; u < 20; ++u) b1[u] = pc[60 + u];
      CP_W40(b0)
      #pragma unroll
      for (int u = 0; u < 20; ++u) b0[u] = pc[80 + u];
      CP_W40(b1)
      #pragma unroll
      for (int u = 0; u < 20; ++u) b1[u] = pc[100 + u];
      CP_W40(b0)
      pc += WPC;
      #pragma unroll
      for (int u = 0; u < 20; ++u) b0[u] = pc[u];
      CP_W40(b1)
    }
  }
  // ---- output chunk: exact f32 reads (coalesced), natural-layout writes ----
  int cg = C0 + lane;
  if (cg < NCC) {
    const float* p = E_ + cg;
    float* py = Y + (size_t)ch * NS + (size_t)cg * LC;
    float b0[U], b1[U];
    #pragma unroll
    for (int u = 0; u < U; ++u) b0[u] = p[(size_t)u * NCC];
    p += (size_t)U * NCC;
    #define CP_OUT(BUF)                                                       \
      _Pragma("unroll")                                                       \
      for (int u = 0; u < U; ++u) {                                           \
        float v = BUF[u];                                                     \
        float lvl = fabsf(v);                                                 \
        E = fmaxf(fmaf(cc.atk, E, lvl), fmaf(cc.rel, E, cc.rho * lvl));       \
        float m = fmaxf(E * cc.invt2, 1.0f);                                  \
        py[u] = v * (sqrtf(sqrtf(m)) * __builtin_amdgcn_rcpf(m));             \
      }                                                                       \
      py += U;
    for (int k = 0; k < 4; ++k) {
      #pragma unroll
      for (int u = 0; u < U; ++u) b1[u] = p[(size_t)u * NCC];
      p += (size_t)U * NCC;
      CP_OUT(b0)
      #pragma unroll
      for (int u = 0; u < U; ++u) b0[u] = p[(size_t)u * NCC];
      p += (size_t)U * NCC;
      CP_OUT(b1)
    }
    #pragma unroll
    for (int u = 0; u < U; ++u) b1[u] = p[(size_t)u * NCC];
    CP_OUT(b0)
    CP_OUT(b1)
  }
}

// ===== Comb: y[n] = x[n] + fb*y[n-d]; phase-parallel chains =====
__global__ __launch_bounds__(256) void comb_kernel(const float* __restrict__ xin,
                                                   float* __restrict__ acc,
                                                   int d, int J, int first) {
  int tid = blockIdx.x * 256 + threadIdx.x;
  int total = 4 * d * J;
  if (tid >= total) return;
  int rch = tid / (d * J);
  int rem = tid - rch * (d * J);
  int j = rem / d;
  int p = rem - j * d;
  const float* xi = xin + (size_t)(4 + rch) * NS;
  float* ao = acc + (size_t)rch * NS;
  int K = (NS - p + d - 1) / d;
  int kstart = j * CB;
  if (kstart >= K) return;
  int kend = kstart + CB; if (kend > K) kend = K;
  float yv = 0.f;
  int k = (j == 0) ? 0 : (kstart - RVW);
  int n = k * d + p;
  if (j != 0) {
    #pragma unroll 16
    for (; k < kstart; ++k, n += d) yv = fmaf(FBC, yv, xi[n]);
  }
  if (first) {
    #pragma unroll 16
    for (; k < kend; ++k, n += d) { yv = fmaf(FBC, yv, xi[n]); ao[n] = yv; }
  } else {
    #pragma unroll 16
    for (; k < kend; ++k, n += d) { yv = fmaf(FBC, yv, xi[n]); ao[n] += yv; }
  }
}

// ===== Allpass: y[n<d]=0; y[n] = -fb*u[n] + u[n-d] + fb*y[n-d] =====
__global__ __launch_bounds__(256) void allpass_kernel(const float* __restrict__ xin,
                                                      float* __restrict__ yout,
                                                      int d, int J, float inscale) {
  int tid = blockIdx.x * 256 + threadIdx.x;
  int total = 4 * d * J;
  if (tid >= total) return;
  int rch = tid / (d * J);
  int rem = tid - rch * (d * J);
  int j = rem / d;
  int p = rem - j * d;
  const float* xi = xin + (size_t)rch * NS;
  float* yo = yout + (size_t)rch * NS;
  int K = (NS - p + d - 1) / d;
  int kstart = j * CB;
  if (kstart >= K) return;
  int kend = kstart + CB; if (kend > K) kend = K;
  float yv = 0.f;
  int k;
  if (j == 0) { yo[p] = 0.f; k = 1; }
  else        { k = kstart - RVW; }
  int n = k * d + p;
  if (j != 0) {
    #pragma unroll 16
    for (; k < kstart; ++k, n += d) {
      float u  = inscale * xi[n];
      float up = inscale * xi[n - d];
      yv = fmaf(FBC, yv, fmaf(-FBC, u, up));
    }
  }
  #pragma unroll 16
  for (; k < kend; ++k, n += d) {
    float u  = inscale * xi[n];
    float up = inscale * xi[n - d];
    yv = fmaf(FBC, yv, fmaf(-FBC, u, up));
    yo[n] = yv;
  }
}

// ===== Final mix (gains folded in) =====
__global__ __launch_bounds__(256) void mix_kernel(const float* __restrict__ cp,
                                                  const float* __restrict__ wet,
                                                  const float* __restrict__ vol,
                                                  const float* __restrict__ pan,
                                                  float* __restrict__ out) {
  int i = blockIdx.x * 256 + threadIdx.x;
  if (i >= NS / 4) return;
  size_t n = (size_t)i * 4;
  float g[8];
  #pragma unroll
  for (int t = 0; t < 4; ++t) {
    float angle = (pan[t] + 1.0f) * 0.25f * 3.14159265358979323846f;
    g[2 * t]     = vol[t] * cosf(angle);
    g[2 * t + 1] = vol[t] * sinf(angle);
  }
  const float CEIL = 0.89125093813374556f;
  float4 t0l = *(const float4*)(cp + 0 * (size_t)NS + n);
  float4 t0r = *(const float4*)(cp + 1 * (size_t)NS + n);
  float4 t1l = *(const float4*)(cp + 2 * (size_t)NS + n);
  float4 t1r = *(const float4*)(cp + 3 * (size_t)NS + n);
  float4 t2l = *(const float4*)(cp + 4 * (size_t)NS + n);
  float4 t2r = *(const float4*)(cp + 5 * (size_t)NS + n);
  float4 t3l = *(const float4*)(cp + 6 * (size_t)NS + n);
  float4 t3r = *(const float4*)(cp + 7 * (size_t)NS + n);
  float4 w2l = *(const float4*)(wet + 0 * (size_t)NS + n);
  float4 w2r = *(const float4*)(wet + 1 * (size_t)NS + n);
  float4 w3l = *(const float4*)(wet + 2 * (size_t)NS + n);
  float4 w3r = *(const float4*)(wet + 3 * (size_t)NS + n);
  float4 outl, outr;
  float* pl = &outl.x; float* pr = &outr.x;
  const float* a0 = &t0l.x; const float* a1 = &t0r.x;
  const float* a2 = &t1l.x; const float* a3 = &t1r.x;
  const float* a4 = &t2l.x; const float* a5 = &t2r.x;
  const float* a6 = &t3l.x; const float* a7 = &t3r.x;
  const float* b4 = &w2l.x; const float* b5 = &w2r.x;
  const float* b6 = &w3l.x; const float* b7 = &w3r.x;
  #pragma unroll
  for (int cc = 0; cc < 4; ++cc) {
    float x4 = 0.7f * a4[cc] + 0.3f * b4[cc];
    float x5 = 0.7f * a5[cc] + 0.3f * b5[cc];
    float x6 = 0.7f * a6[cc] + 0.3f * b6[cc];
    float x7 = 0.7f * a7[cc] + 0.3f * b7[cc];
    float Lv = g[0] * a0[cc] + g[2] * a2[cc] + g[4] * x4 + g[6] * x6;
    float Rv = g[1] * a1[cc] + g[3] * a3[cc] + g[5] * x5 + g[7] * x7;
    pl[cc] = fminf(fmaxf(Lv, -CEIL), CEIL);
    pr[cc] = fminf(fmaxf(Rv, -CEIL), CEIL);
  }
  *(float4*)(out + n) = outl;
  *(float4*)(out + (size_t)NS + n) = outr;
}

// ---------------- Host side ----------------
static void peak_coefs(double f, double gdb, double q, float* o) {
  double A  = pow(10.0, gdb / 40.0);
  double w0 = 2.0 * M_PI * f / 48000.0;
  double al = sin(w0) / (2.0 * q);
  double a0 = 1.0 + al / A;
  o[0] = (float)((1.0 + al * A) / a0);
  o[1] = (float)(-2.0 * cos(w0) / a0);
  o[2] = (float)((1.0 - al * A) / a0);
  o[3] = (float)(-2.0 * cos(w0) / a0);
  o[4] = (float)((1.0 - al / A) / a0);
}

extern "C" void kernel_launch(void* const* d_in, const int* in_sizes, int n_in,
                              void* d_out, int out_size, void* d_ws, size_t ws_size,
                              hipStream_t stream) {
  const float* tracks = (const float*)d_in[0];
  const float* vols   = (const float*)d_in[1];
  const float* pans   = (const float*)d_in[2];
  float* out = (float*)d_out;
  float* w = (float*)d_ws;
  // ws: [0,8N) XT -> comp output Y; [8N,16N) ET -> comb acc [8N,12N),
  //     ap240 [12N,16N), ap81/wet [8N,12N).
  float* XT    = w;
  float* ET    = w + (size_t)8 * NS;
  float* cpbuf = w;
  float* combb = w + (size_t)8 * NS;
  float* apb   = w + (size_t)12 * NS;
  float* wet2  = w + (size_t)8 * NS;

  Coefs cf;
  const float ident[5] = {1.f, 0.f, 0.f, 0.f, 0.f};
  const double P[4][3][3] = {
    {{300, -3, 0.7}, {3000, 3, 1.0}, {8000, 2, 0.7}},
    {{80, 2, 0.7},   {5000, 1, 1.0}, {0, 0, 0}},
    {{200, -2, 0.7}, {6000, -1, 0.7}, {0, 0, 0}},
    {{1000, 2, 1.0}, {0, 0, 0},      {0, 0, 0}},
  };
  const int nb[4] = {3, 2, 2, 1};
  for (int t = 0; t < 4; ++t)
    for (int s = 0; s < 3; ++s) {
      if (s < nb[t]) peak_coefs(P[t][s][0], P[t][s][1], P[t][s][2], cf.c[s][t]);
      else for (int q = 0; q < 5; ++q) cf.c[s][t][q] = ident[q];
    }

  CompC cc;
  double atk = exp(-1.0 / 480.0), rel = exp(-1.0 / 4800.0);
  double oatk = 1.0 - atk, orel = 1.0 - rel;
  double invt = 1.0 / (pow(10.0, -18.0 / 20.0) + 1e-8);
  cc.atk   = (float)atk;
  cc.rel   = (float)rel;
  cc.rho   = (float)(orel / oatk);
  cc.invt2 = (float)(oatk * invt);

  hipLaunchKernelGGL(transpose_in, dim3(8 * 15 * 375), dim3(256), 0, stream,
                     tracks, XT);
  hipLaunchKernelGGL(eq_kernel, dim3(8 * CHB), dim3(64), 0, stream,
                     XT, ET, cf);
  hipLaunchKernelGGL(comp_kernel, dim3(8 * CHB), dim3(64), 0, stream,
                     ET, cpbuf, cc);

  const int combd[4] = {1440, 1627, 1828, 2030};
  for (int i = 0; i < 4; ++i) {
    int d = combd[i];
    int K = (NS + d - 1) / d;
    int J = (K + CB - 1) / CB;
    int total = 4 * d * J;
    hipLaunchKernelGGL(comb_kernel, dim3((total + 255) / 256), dim3(256), 0, stream,
                       cpbuf, combb, d, J, (i == 0) ? 1 : 0);
  }
  {
    int d = 240, K = (NS + d - 1) / d, J = (K + CB - 1) / CB, total = 4 * d * J;
    hipLaunchKernelGGL(allpass_kernel, dim3((total + 255) / 256), dim3(256), 0, stream,
                       combb, apb, d, J, 0.25f);
  }
  {
    int d = 81, K = (NS + d - 1) / d, J = (K + CB - 1) / CB, total = 4 * d * J;
    hipLaunchKernelGGL(allpass_kernel, dim3((total + 255) / 256), dim3(256), 0, stream,
                       apb, wet2, d, J, 1.0f);
  }
  hipLaunchKernelGGL(mix_kernel, dim3((NS / 4 + 255) / 256), dim3(256), 0, stream,
                     cpbuf, wet2, vols, pans, out);
}

// Round 8
// 483.838 us; speedup vs baseline: 2.4487x; 1.1047x over previous
//
#include <hip/hip_runtime.h>
#include <math.h>

#define NS  1440000
#define LC  240         // chunk length
#define NCC 6000        // chunks per channel; LC*NCC == NS
#define CHB 94          // ceil(NCC/64) eq chunk-blocks per channel
#define CPW 47          // comp warm chunks = 11280 samples (accuracy-pinned)
#define EQW 6           // eq warm chunks = 1440 samples
#define EWIN (64 + EQW - 1)        // 69 eq window columns (+1 pad)
#define CPB 256                     // comp chunks per block (256 lanes)
#define CWIN2 (CPB + CPW - 1)       // 302 comp window columns (+1 pad)
#define WPC 121         // LDS words per column (120 data + 1 pad; 25L%32 -> 2-way free)
#define U   24          // strip size for output passes; 240 = 2*U*5

// ---- Reverb chain chunking ----
#define CB  64
#define RVW 40         // 0.6^40 ~ 1e-9
#define FBC 0.6f

typedef float v2f __attribute__((ext_vector_type(2)));

struct Coefs { float c[3][4][5]; };
struct CompC { float atk, rel, rho, invt2; };

__device__ inline unsigned int f32_to_bf16_rtne(float v) {
  unsigned int b = __float_as_uint(v);
  return (b + 0x7fffu + ((b >> 16) & 1u)) >> 16;
}

// ===== EQ: natural-layout fill (coalesced col sweeps), bf16 LDS warm, f32 output =====
#define EQ_STEPT(VV)                                                       \
  {                                                                        \
    float v = (VV);                                                        \
    _Pragma("unroll")                                                      \
    for (int st = 0; st < NST; ++st) {                                     \
      float ya = fmaf(c[st][0], v, z[st][0]);                              \
      z[st][0] = fmaf(c[st][1], v, z[st][1]) - c[st][3] * ya;              \
      z[st][1] = fmaf(c[st][2], v, -(c[st][4] * ya));                      \
      v = ya;                                                              \
    }                                                                      \
    vout = v;                                                              \
  }

#define EQ_W40T(B)                                                         \
  _Pragma("unroll")                                                        \
  for (int u = 0; u < 20; ++u) {                                           \
    unsigned int wv = (B)[u];                                              \
    float lo = __uint_as_float(wv << 16);                                  \
    float hi = __uint_as_float(wv & 0xffff0000u);                          \
    EQ_STEPT(lo);                                                          \
    EQ_STEPT(hi);                                                          \
  }

template<int NST>
__device__ __forceinline__ void eq_body(const float* __restrict__ X,
                                        float* __restrict__ E,
                                        const Coefs& cf, int tr,
                                        const unsigned int* __restrict__ lds,
                                        int lane, int C0) {
  float c[NST][5];
  #pragma unroll
  for (int st = 0; st < NST; ++st)
    #pragma unroll
    for (int q = 0; q < 5; ++q) c[st][q] = cf.c[st][tr][q];
  float z[NST][2];
  #pragma unroll
  for (int st = 0; st < NST; ++st) { z[st][0] = 0.f; z[st][1] = 0.f; }
  float vout;
  // warm: column (lane+t), 6 strips of 20 words, double-buffered
  {
    unsigned int b0[20], b1[20];
    const unsigned int* pc = lds + lane * WPC;
    #pragma unroll
    for (int u = 0; u < 20; ++u) b0[u] = pc[u];
    for (int t = 0; t < EQW; ++t) {
      #pragma unroll
      for (int u = 0; u < 20; ++u) b1[u] = pc[20 + u];
      EQ_W40T(b0)
      #pragma unroll
      for (int u = 0; u < 20; ++u) b0[u] = pc[40 + u];
      EQ_W40T(b1)
      #pragma unroll
      for (int u = 0; u < 20; ++u) b1[u] = pc[60 + u];
      EQ_W40T(b0)
      #pragma unroll
      for (int u = 0; u < 20; ++u) b0[u] = pc[80 + u];
      EQ_W40T(b1)
      #pragma unroll
      for (int u = 0; u < 20; ++u) b1[u] = pc[100 + u];
      EQ_W40T(b0)
      pc += WPC;
      #pragma unroll
      for (int u = 0; u < 20; ++u) b0[u] = pc[u];   // next col (pad col at end)
      EQ_W40T(b1)
    }
  }
  (void)vout;
  // output chunk: exact f32, per-lane contiguous
  int cg = C0 + lane;
  if (cg < NCC) {
    const float* p = X + (size_t)cg * LC;
    float* q = E + (size_t)cg * LC;
    float b0[U], b1[U];
    #pragma unroll
    for (int u = 0; u < U; ++u) b0[u] = p[u];
    p += U;
    for (int k = 0; k < 4; ++k) {
      #pragma unroll
      for (int u = 0; u < U; ++u) b1[u] = p[u];
      p += U;
      #pragma unroll
      for (int u = 0; u < U; ++u) { EQ_STEPT(b0[u]); q[u] = vout; }
      q += U;
      #pragma unroll
      for (int u = 0; u < U; ++u) b0[u] = p[u];
      p += U;
      #pragma unroll
      for (int u = 0; u < U; ++u) { EQ_STEPT(b1[u]); q[u] = vout; }
      q += U;
    }
    #pragma unroll
    for (int u = 0; u < U; ++u) b1[u] = p[u];
    #pragma unroll
    for (int u = 0; u < U; ++u) { EQ_STEPT(b0[u]); q[u] = vout; }
    q += U;
    #pragma unroll
    for (int u = 0; u < U; ++u) { EQ_STEPT(b1[u]); q[u] = vout; }
  }
}

__global__ __launch_bounds__(64) void eq_kernel(const float* __restrict__ X0,
                                                float* __restrict__ ET, Coefs cf) {
  __shared__ unsigned int lds[(EWIN + 1) * WPC];   // 70*121*4B = 33.9 KB
  int blk = blockIdx.x;
  int ch = blk / CHB, cb = blk % CHB;
  int C0 = cb * 64;
  int lane = threadIdx.x;
  int tr = ch >> 1;
  const float* X = X0 + (size_t)ch * NS;
  float* E = ET + (size_t)ch * NS;
  // fill: natural layout, batched x4; consecutive e -> consecutive addresses
  const int TOT = EWIN * LC;
  for (int base = 0; base < TOT; base += 256) {
    float v[4]; int colE[4], sE[4]; bool val[4];
    #pragma unroll
    for (int i = 0; i < 4; ++i) {
      int e = base + i * 64 + lane;
      val[i] = e < TOT;
      int ec = val[i] ? e : 0;
      colE[i] = ec / LC; sE[i] = ec - colE[i] * LC;
      int cg = C0 - EQW + colE[i];
      v[i] = (val[i] && cg >= 0 && cg < NCC) ? X[(size_t)cg * LC + sE[i]] : 0.f;
    }
    #pragma unroll
    for (int i = 0; i < 4; ++i)
      if (val[i])
        ((unsigned short*)lds)[colE[i] * (2 * WPC) + sE[i]] =
            (unsigned short)f32_to_bf16_rtne(v[i]);
  }
  __syncthreads();
  if (tr == 0)      eq_body<3>(X, E, cf, tr, lds, lane, C0);
  else if (tr == 3) eq_body<1>(X, E, cf, tr, lds, lane, C0);
  else              eq_body<2>(X, E, cf, tr, lds, lane, C0);
}

// ===== Compressor: 256-lane shared window, packed atk/rel math, single round =====
#define CP_STEP1(VX)                                                       \
  { v2f t = OQ * (v2f){(VX), (VX)};                                        \
    v2f e2 = AR * (v2f){E, E} + t;                                         \
    E = fmaxf(e2.x, e2.y); }

#define CP_W40(B)                                                          \
  _Pragma("unroll")                                                        \
  for (int u = 0; u < 20; ++u) {                                           \
    unsigned int wv = (B)[u];                                              \
    float lo = __uint_as_float(wv << 16);                                  \
    float hi = __uint_as_float(wv & 0xffff0000u);                          \
    CP_STEP1(lo);                                                          \
    CP_STEP1(hi);                                                          \
  }

__global__ __launch_bounds__(256) void comp_kernel(const float* __restrict__ ET,
                                                   float* __restrict__ Y, CompC cc) {
  extern __shared__ unsigned int lds[];            // (CWIN2+1)*WPC words = 146.6 KB
  int blk = blockIdx.x;
  int ch = blk / 24, cb = blk % 24;
  int C0 = cb * CPB;
  int tid = threadIdx.x;
  const float* E_ = ET + (size_t)ch * NS;
  const v2f AR = {cc.atk, cc.rel};
  const v2f OQ = {1.0f, cc.rho};
  // fill: natural layout, |x| as bf16, batched x4
  const int TOT2 = CWIN2 * LC;                     // 72480
  for (int base = 0; base < TOT2; base += 1024) {
    float v[4]; int colE[4], sE[4]; bool val[4];
    #pragma unroll
    for (int i = 0; i < 4; ++i) {
      int e = base + i * 256 + tid;
      val[i] = e < TOT2;
      int ec = val[i] ? e : 0;
      colE[i] = ec / LC; sE[i] = ec - colE[i] * LC;
      int cg = C0 - CPW + colE[i];
      v[i] = (val[i] && cg >= 0 && cg < NCC) ? E_[(size_t)cg * LC + sE[i]] : 0.f;
    }
    #pragma unroll
    for (int i = 0; i < 4; ++i)
      if (val[i]) {
        unsigned int b = __float_as_uint(v[i]) & 0x7fffffffu;
        b = (b + 0x7fffu + ((b >> 16) & 1u)) >> 16;
        ((unsigned short*)lds)[colE[i] * (2 * WPC) + sE[i]] = (unsigned short)b;
      }
  }
  __syncthreads();
  float E = 0.f;   // env / oatk
  {
    unsigned int b0[20], b1[20];
    const unsigned int* pc = lds + tid * WPC;
    #pragma unroll
    for (int u = 0; u < 20; ++u) b0[u] = pc[u];
    for (int t = 0; t < CPW; ++t) {
      #pragma unroll
      for (int u = 0; u < 20; ++u) b1[u] = pc[20 + u];
      CP_W40(b0)
      #pragma unroll
      for (int u = 0; u < 20; ++u) b0[u] = pc[40 + u];
      CP_W40(b1)
      #pragma unroll
      for (int u = 0; u < 20; ++u) b1[u] = pc[60 + u];
      CP_W40(b0)
      #pragma unroll
      for (int u = 0; u < 20; ++u) b0[u] = pc[80 + u];
      CP_W40(b1)
      #pragma unroll
      for (int u = 0; u < 20; ++u) b1[u] = pc[100 + u];
      CP_W40(b0)
      pc += WPC;
      #pragma unroll
      for (int u = 0; u < 20; ++u) b0[u] = pc[u];
      CP_W40(b1)
    }
  }
  // output chunk: exact f32, per-lane contiguous read AND write
  int cg = C0 + tid;
  if (cg < NCC) {
    const float* p = E_ + (size_t)cg * LC;
    float* py = Y + (size_t)ch * NS + (size_t)cg * LC;
    float b0[U], b1[U];
    #pragma unroll
    for (int u = 0; u < U; ++u) b0[u] = p[u];
    p += U;
    #define CP_OUT(BUF)                                                       \
      _Pragma("unroll")                                                       \
      for (int u = 0; u < U; ++u) {                                           \
        float v = BUF[u];                                                     \
        float lvl = fabsf(v);                                                 \
        E = fmaxf(fmaf(cc.atk, E, lvl), fmaf(cc.rel, E, cc.rho * lvl));       \
        float m = fmaxf(E * cc.invt2, 1.0f);                                  \
        py[u] = v * (sqrtf(sqrtf(m)) * __builtin_amdgcn_rcpf(m));             \
      }                                                                       \
      py += U;
    for (int k = 0; k < 4; ++k) {
      #pragma unroll
      for (int u = 0; u < U; ++u) b1[u] = p[u];
      p += U;
      CP_OUT(b0)
      #pragma unroll
      for (int u = 0; u < U; ++u) b0[u] = p[u];
      p += U;
      CP_OUT(b1)
    }
    #pragma unroll
    for (int u = 0; u < U; ++u) b1[u] = p[u];
    CP_OUT(b0)
    CP_OUT(b1)
  }
}

// ===== Fused 4-comb: zeroed acc + unsafeAtomicAdd (order-free accumulation) =====
__global__ __launch_bounds__(256) void comb_fused(const float* __restrict__ xin,
                                                  float* __restrict__ acc,
                                                  int4 dv, int4 Jv, int4 bv, int total) {
  int tid = blockIdx.x * 256 + threadIdx.x;
  if (tid >= total) return;
  int d, J, rel;
  if      (tid < bv.y) { d = dv.x; J = Jv.x; rel = tid; }
  else if (tid < bv.z) { d = dv.y; J = Jv.y; rel = tid - bv.y; }
  else if (tid < bv.w) { d = dv.z; J = Jv.z; rel = tid - bv.z; }
  else                 { d = dv.w; J = Jv.w; rel = tid - bv.w; }
  int rch = rel / (d * J);
  int rem = rel - rch * (d * J);
  int j = rem / d;
  int p = rem - j * d;
  const float* xi = xin + (size_t)(4 + rch) * NS;
  float* ao = acc + (size_t)rch * NS;
  int K = (NS - p + d - 1) / d;
  int kstart = j * CB;
  if (kstart >= K) return;
  int kend = kstart + CB; if (kend > K) kend = K;
  float yv = 0.f;
  int k = (j == 0) ? 0 : (kstart - RVW);
  int n = k * d + p;
  if (j != 0) {
    #pragma unroll 16
    for (; k < kstart; ++k, n += d) yv = fmaf(FBC, yv, xi[n]);
  }
  #pragma unroll 16
  for (; k < kend; ++k, n += d) {
    yv = fmaf(FBC, yv, xi[n]);
    unsafeAtomicAdd(&ao[n], yv);
  }
}

// ===== Allpass =====
__global__ __launch_bounds__(256) void allpass_kernel(const float* __restrict__ xin,
                                                      float* __restrict__ yout,
                                                      int d, int J, float inscale) {
  int tid = blockIdx.x * 256 + threadIdx.x;
  int total = 4 * d * J;
  if (tid >= total) return;
  int rch = tid / (d * J);
  int rem = tid - rch * (d * J);
  int j = rem / d;
  int p = rem - j * d;
  const float* xi = xin + (size_t)rch * NS;
  float* yo = yout + (size_t)rch * NS;
  int K = (NS - p + d - 1) / d;
  int kstart = j * CB;
  if (kstart >= K) return;
  int kend = kstart + CB; if (kend > K) kend = K;
  float yv = 0.f;
  int k;
  if (j == 0) { yo[p] = 0.f; k = 1; }
  else        { k = kstart - RVW; }
  int n = k * d + p;
  if (j != 0) {
    #pragma unroll 16
    for (; k < kstart; ++k, n += d) {
      float u  = inscale * xi[n];
      float up = inscale * xi[n - d];
      yv = fmaf(FBC, yv, fmaf(-FBC, u, up));
    }
  }
  #pragma unroll 16
  for (; k < kend; ++k, n += d) {
    float u  = inscale * xi[n];
    float up = inscale * xi[n - d];
    yv = fmaf(FBC, yv, fmaf(-FBC, u, up));
    yo[n] = yv;
  }
}

// ===== Final mix (gains inline) =====
__global__ __launch_bounds__(256) void mix_kernel(const float* __restrict__ cp,
                                                  const float* __restrict__ wet,
                                                  const float* __restrict__ vol,
                                                  const float* __restrict__ pan,
                                                  float* __restrict__ out) {
  int i = blockIdx.x * 256 + threadIdx.x;
  if (i >= NS / 4) return;
  size_t n = (size_t)i * 4;
  float g[8];
  #pragma unroll
  for (int t = 0; t < 4; ++t) {
    float angle = (pan[t] + 1.0f) * 0.25f * 3.14159265358979323846f;
    g[2 * t]     = vol[t] * cosf(angle);
    g[2 * t + 1] = vol[t] * sinf(angle);
  }
  const float CEIL = 0.89125093813374556f;
  float4 t0l = *(const float4*)(cp + 0 * (size_t)NS + n);
  float4 t0r = *(const float4*)(cp + 1 * (size_t)NS + n);
  float4 t1l = *(const float4*)(cp + 2 * (size_t)NS + n);
  float4 t1r = *(const float4*)(cp + 3 * (size_t)NS + n);
  float4 t2l = *(const float4*)(cp + 4 * (size_t)NS + n);
  float4 t2r = *(const float4*)(cp + 5 * (size_t)NS + n);
  float4 t3l = *(const float4*)(cp + 6 * (size_t)NS + n);
  float4 t3r = *(const float4*)(cp + 7 * (size_t)NS + n);
  float4 w2l = *(const float4*)(wet + 0 * (size_t)NS + n);
  float4 w2r = *(const float4*)(wet + 1 * (size_t)NS + n);
  float4 w3l = *(const float4*)(wet + 2 * (size_t)NS + n);
  float4 w3r = *(const float4*)(wet + 3 * (size_t)NS + n);
  float4 outl, outr;
  float* pl = &outl.x; float* pr = &outr.x;
  const float* a0 = &t0l.x; const float* a1 = &t0r.x;
  const float* a2 = &t1l.x; const float* a3 = &t1r.x;
  const float* a4 = &t2l.x; const float* a5 = &t2r.x;
  const float* a6 = &t3l.x; const float* a7 = &t3r.x;
  const float* b4 = &w2l.x; const float* b5 = &w2r.x;
  const float* b6 = &w3l.x; const float* b7 = &w3r.x;
  #pragma unroll
  for (int cc = 0; cc < 4; ++cc) {
    float x4 = 0.7f * a4[cc] + 0.3f * b4[cc];
    float x5 = 0.7f * a5[cc] + 0.3f * b5[cc];
    float x6 = 0.7f * a6[cc] + 0.3f * b6[cc];
    float x7 = 0.7f * a7[cc] + 0.3f * b7[cc];
    float Lv = g[0] * a0[cc] + g[2] * a2[cc] + g[4] * x4 + g[6] * x6;
    float Rv = g[1] * a1[cc] + g[3] * a3[cc] + g[5] * x5 + g[7] * x7;
    pl[cc] = fminf(fmaxf(Lv, -CEIL), CEIL);
    pr[cc] = fminf(fmaxf(Rv, -CEIL), CEIL);
  }
  *(float4*)(out + n) = outl;
  *(float4*)(out + (size_t)NS + n) = outr;
}

// ---------------- Host side ----------------
static void peak_coefs(double f, double gdb, double q, float* o) {
  double A  = pow(10.0, gdb / 40.0);
  double w0 = 2.0 * M_PI * f / 48000.0;
  double al = sin(w0) / (2.0 * q);
  double a0 = 1.0 + al / A;
  o[0] = (float)((1.0 + al * A) / a0);
  o[1] = (float)(-2.0 * cos(w0) / a0);
  o[2] = (float)((1.0 - al * A) / a0);
  o[3] = (float)(-2.0 * cos(w0) / a0);
  o[4] = (float)((1.0 - al / A) / a0);
}

extern "C" void kernel_launch(void* const* d_in, const int* in_sizes, int n_in,
                              void* d_out, int out_size, void* d_ws, size_t ws_size,
                              hipStream_t stream) {
  const float* tracks = (const float*)d_in[0];
  const float* vols   = (const float*)d_in[1];
  const float* pans   = (const float*)d_in[2];
  float* out = (float*)d_out;
  float* w = (float*)d_ws;
  // ws: [0,8N) comp output Y; [8N,16N) ET -> comb acc [8N,12N),
  //     ap240 [12N,16N), ap81/wet [8N,12N).
  float* ET    = w + (size_t)8 * NS;
  float* cpbuf = w;
  float* combb = w + (size_t)8 * NS;
  float* apb   = w + (size_t)12 * NS;
  float* wet2  = w + (size_t)8 * NS;

  Coefs cf;
  const float ident[5] = {1.f, 0.f, 0.f, 0.f, 0.f};
  const double P[4][3][3] = {
    {{300, -3, 0.7}, {3000, 3, 1.0}, {8000, 2, 0.7}},
    {{80, 2, 0.7},   {5000, 1, 1.0}, {0, 0, 0}},
    {{200, -2, 0.7}, {6000, -1, 0.7}, {0, 0, 0}},
    {{1000, 2, 1.0}, {0, 0, 0},      {0, 0, 0}},
  };
  const int nb[4] = {3, 2, 2, 1};
  for (int t = 0; t < 4; ++t)
    for (int s = 0; s < 3; ++s) {
      if (s < nb[t]) peak_coefs(P[t][s][0], P[t][s][1], P[t][s][2], cf.c[s][t]);
      else for (int q = 0; q < 5; ++q) cf.c[s][t][q] = ident[q];
    }

  CompC cc;
  double atk = exp(-1.0 / 480.0), rel = exp(-1.0 / 4800.0);
  double oatk = 1.0 - atk, orel = 1.0 - rel;
  double invt = 1.0 / (pow(10.0, -18.0 / 20.0) + 1e-8);
  cc.atk   = (float)atk;
  cc.rel   = (float)rel;
  cc.rho   = (float)(orel / oatk);
  cc.invt2 = (float)(oatk * invt);

  hipLaunchKernelGGL(eq_kernel, dim3(8 * CHB), dim3(64), 0, stream,
                     tracks, ET, cf);

  const int compLDS = (CWIN2 + 1) * WPC * 4;       // 146652 B
  hipFuncSetAttribute((const void*)comp_kernel,
                      hipFuncAttributeMaxDynamicSharedMemorySize, compLDS);
  hipLaunchKernelGGL(comp_kernel, dim3(8 * 24), dim3(256), compLDS, stream,
                     ET, cpbuf, cc);

  // fused combs: zero acc then atomic-accumulate all 4 combs in one launch
  hipMemsetAsync(combb, 0, (size_t)4 * NS * sizeof(float), stream);
  {
    const int ds[4] = {1440, 1627, 1828, 2030};
    int Js[4], base[4], tot = 0;
    for (int i = 0; i < 4; ++i) {
      int K = (NS + ds[i] - 1) / ds[i];
      Js[i] = (K + CB - 1) / CB;
      base[i] = tot;
      tot += 4 * ds[i] * Js[i];
    }
    int4 dv = {ds[0], ds[1], ds[2], ds[3]};
    int4 Jv = {Js[0], Js[1], Js[2], Js[3]};
    int4 bv = {base[0], base[1], base[2], base[3]};
    hipLaunchKernelGGL(comb_fused, dim3((tot + 255) / 256), dim3(256), 0, stream,
                       cpbuf, combb, dv, Jv, bv, tot);
  }
  {
    int d = 240, K = (NS + d - 1) / d, J = (K + CB - 1) / CB, total = 4 * d * J;
    hipLaunchKernelGGL(allpass_kernel, dim3((total + 255) / 256), dim3(256), 0, stream,
                       combb, apb, d, J, 0.25f);
  }
  {
    int d = 81, K = (NS + d - 1) / d, J = (K + CB - 1) / CB, total = 4 * d * J;
    hipLaunchKernelGGL(allpass_kernel, dim3((total + 255) / 256), dim3(256), 0, stream,
                       apb, wet2, d, J, 1.0f);
  }
  hipLaunchKernelGGL(mix_kernel, dim3((NS / 4 + 255) / 256), dim3(256), 0, stream,
                     cpbuf, wet2, vols, pans, out);
}